// Round 2
// baseline (560.138 us; speedup 1.0000x reference)
//
#include <hip/hip_runtime.h>

// CrossAttention B=8, N=M=2048, D=HID=OUT=1024. fp32 in / fp32 out, int32 mask.
//
// Round-7: round-6's tile body had 4 raw barriers/tile, serializing
// {LDS-read wait -> MFMA} every phase (MfmaUtil 26%). This round: ONE
// region + ONE barrier per K-tile:
//   { issue 4 gl_lds(t+3); issue all 12 ds_read_b128; setprio(1);
//     32 MFMA (+8 rowsum for EPI2); setprio(0); s_waitcnt vmcnt(4); s_barrier }
// The compiler's fine-grained lgkmcnt(N) interleaves ds_reads with MFMAs, so
// LDS service time hides under the matrix pipe instead of being exposed
// behind a barrier. Ring/staging invariants (4-deep ring, stage t+3 during t):
//   - safety: reads of buf (t-1)&3 complete before each wave's own MFMAs
//     (compiler lgkm waits), hence before the end-of-tile barrier; staging
//     into (t+3)&3 == (t-1)&3 happens after that barrier. 1 barrier/tile.
//   - vmcnt(4) at end of tile t leaves only t+3's 4 loads outstanding ->
//     t+2 landed one full tile before its reads.  Tail: vmcnt(4), (0), none.
//   - prologue: stage tiles 0,1,2 (12 loads), vmcnt(8) -> tile 0 landed.
// XOR swizzle unchanged (0 bank conflicts measured): LDS slot (row r, blk c)
// holds global k-block c ^ ((r>>1)&3); reads use kb = (quad^((lr>>1)&3))<<3.
//
// Fused math unchanged (round-5 verified):
//   S epilogue: p = exp((mask ? s : -1e10)/32) f16 (exact softmax algebra).
//   out GEMM: rowsum(P) via one ones-vector MFMA per A-frag (same C/D slots);
//   epilogue scales by 1/rowsum.
//
// Buffers (peak ws = 100,663,296 B):
//   h1f ws@0           33.5 MB (dead after Q)    -> Vt reuses
//   h2f ws@33,554,432  33.5 MB (dead after Vt)
//   Wf  ws@67,108,864   6.3 MB (dead after Vt)
//   SP  ws@33,554,432  67.1 MB (over dead h2f+Wf)
//   Qf  d_out lo half, Kp d_out hi half (dead before final fp32 write)

using f16   = _Float16;
using f16x4 = __attribute__((ext_vector_type(4))) _Float16;
using f16x8 = __attribute__((ext_vector_type(8))) _Float16;
using f32x4 = __attribute__((ext_vector_type(4))) float;

typedef unsigned int u32_g __attribute__((address_space(1)));
typedef unsigned int u32_l __attribute__((address_space(3)));

__device__ __forceinline__ void gl_lds16(const f16* g, f16* l) {
    __builtin_amdgcn_global_load_lds((const u32_g*)g, (u32_l*)l, 16, 0, 0);
}

#define FENCE() asm volatile("" ::: "memory")
#define BAR()   do { FENCE(); __builtin_amdgcn_s_barrier(); FENCE(); } while (0)

// 16 MFMA: rows RG_..RG_+3 x all 4 col-groups (+4 rowsum MFMA for EPI 2).
#define MFMA_HALF(A0_, A1_, A2_, A3_, RG_)                                               \
  do {                                                                                   \
    if constexpr (EPI == 2) {                                                            \
      rs[RG_+0] = __builtin_amdgcn_mfma_f32_16x16x32_f16(A0_, bones, rs[RG_+0], 0,0,0);  \
      rs[RG_+1] = __builtin_amdgcn_mfma_f32_16x16x32_f16(A1_, bones, rs[RG_+1], 0,0,0);  \
      rs[RG_+2] = __builtin_amdgcn_mfma_f32_16x16x32_f16(A2_, bones, rs[RG_+2], 0,0,0);  \
      rs[RG_+3] = __builtin_amdgcn_mfma_f32_16x16x32_f16(A3_, bones, rs[RG_+3], 0,0,0);  \
    }                                                                                    \
    acc[RG_+0][0] = __builtin_amdgcn_mfma_f32_16x16x32_f16(A0_, b0, acc[RG_+0][0],0,0,0);\
    acc[RG_+0][1] = __builtin_amdgcn_mfma_f32_16x16x32_f16(A0_, b1, acc[RG_+0][1],0,0,0);\
    acc[RG_+0][2] = __builtin_amdgcn_mfma_f32_16x16x32_f16(A0_, b2, acc[RG_+0][2],0,0,0);\
    acc[RG_+0][3] = __builtin_amdgcn_mfma_f32_16x16x32_f16(A0_, b3, acc[RG_+0][3],0,0,0);\
    acc[RG_+1][0] = __builtin_amdgcn_mfma_f32_16x16x32_f16(A1_, b0, acc[RG_+1][0],0,0,0);\
    acc[RG_+1][1] = __builtin_amdgcn_mfma_f32_16x16x32_f16(A1_, b1, acc[RG_+1][1],0,0,0);\
    acc[RG_+1][2] = __builtin_amdgcn_mfma_f32_16x16x32_f16(A1_, b2, acc[RG_+1][2],0,0,0);\
    acc[RG_+1][3] = __builtin_amdgcn_mfma_f32_16x16x32_f16(A1_, b3, acc[RG_+1][3],0,0,0);\
    acc[RG_+2][0] = __builtin_amdgcn_mfma_f32_16x16x32_f16(A2_, b0, acc[RG_+2][0],0,0,0);\
    acc[RG_+2][1] = __builtin_amdgcn_mfma_f32_16x16x32_f16(A2_, b1, acc[RG_+2][1],0,0,0);\
    acc[RG_+2][2] = __builtin_amdgcn_mfma_f32_16x16x32_f16(A2_, b2, acc[RG_+2][2],0,0,0);\
    acc[RG_+2][3] = __builtin_amdgcn_mfma_f32_16x16x32_f16(A2_, b3, acc[RG_+2][3],0,0,0);\
    acc[RG_+3][0] = __builtin_amdgcn_mfma_f32_16x16x32_f16(A3_, b0, acc[RG_+3][0],0,0,0);\
    acc[RG_+3][1] = __builtin_amdgcn_mfma_f32_16x16x32_f16(A3_, b1, acc[RG_+3][1],0,0,0);\
    acc[RG_+3][2] = __builtin_amdgcn_mfma_f32_16x16x32_f16(A3_, b2, acc[RG_+3][2],0,0,0);\
    acc[RG_+3][3] = __builtin_amdgcn_mfma_f32_16x16x32_f16(A3_, b3, acc[RG_+3][3],0,0,0);\
  } while (0)

// One K-tile, single region + single barrier. Staging issued first (VMEM
// queue fills early), then all 12 ds_reads; compiler interleaves lgkm waits
// with the MFMA cluster. VM_ is the counted vmcnt before the barrier.
#define TILE_BODY(T_, STG_, VM_)                                                         \
  {                                                                                      \
    const f16* bufA_ = smem + ((T_) & 3) * 16384;                                        \
    const f16* bufB_ = bufA_ + 8192;                                                     \
    if (STG_) {                                                                          \
      f16* dA_ = ldsAw + ((T_ + 3) & 3) * 16384;                                         \
      f16* dB_ = ldsBw + ((T_ + 3) & 3) * 16384;                                         \
      const f16* gA_ = gAs + (long)(T_ + 3) * 32;                                        \
      const f16* gB_ = gBs + (long)(T_ + 3) * 32;                                        \
      gl_lds16(gA_, dA_);                                                                \
      gl_lds16(gA_ + sweep, dA_ + 4096);                                                 \
      gl_lds16(gB_, dB_);                                                                \
      gl_lds16(gB_ + sweep, dB_ + 4096);                                                 \
    }                                                                                    \
    f16x8 a0_, a1_, a2_, a3_, a4_, a5_, a6_, a7_, b0, b1, b2, b3;                        \
    a0_ = *(const f16x8*)(bufA_ + offA);                                                 \
    a1_ = *(const f16x8*)(bufA_ + offA + 512);                                           \
    a2_ = *(const f16x8*)(bufA_ + offA + 1024);                                          \
    a3_ = *(const f16x8*)(bufA_ + offA + 1536);                                          \
    b0  = *(const f16x8*)(bufB_ + offB);                                                 \
    b1  = *(const f16x8*)(bufB_ + offB + 512);                                           \
    b2  = *(const f16x8*)(bufB_ + offB + 1024);                                          \
    b3  = *(const f16x8*)(bufB_ + offB + 1536);                                          \
    a4_ = *(const f16x8*)(bufA_ + offA + 2048);                                          \
    a5_ = *(const f16x8*)(bufA_ + offA + 2560);                                          \
    a6_ = *(const f16x8*)(bufA_ + offA + 3072);                                          \
    a7_ = *(const f16x8*)(bufA_ + offA + 3584);                                          \
    __builtin_amdgcn_s_setprio(1);                                                       \
    MFMA_HALF(a0_, a1_, a2_, a3_, 0);                                                    \
    MFMA_HALF(a4_, a5_, a6_, a7_, 4);                                                    \
    __builtin_amdgcn_s_setprio(0);                                                       \
    asm volatile(VM_ ::: "memory");                                                      \
    BAR();                                                                               \
  }

// NT GEMM: C = A * B^T. A:(MxK) f16, B:(NxK) f16, row-major. 256x256 tile.
// EPI 0: f16 C.
// EPI 1: f16 C = exp((mask ? acc : -1e10) * 1/32)   [S GEMM]
// EPI 2: fp32 C = acc / rowsum(A)                   [out GEMM, ones-MFMA sums]
// GDEC 0: 3D grid. GDEC 1: 1D grid, z=l&7, x=(l>>3)&(2^LGX-1), y=l>>(3+LGX).
template <int EPI, int GDEC, int LGX>
__global__ __launch_bounds__(512, 2)
void gemm256_nt_f16(const f16* __restrict__ A, const f16* __restrict__ B,
                    void* __restrict__ Cv, const int* __restrict__ Mask,
                    int N, int K, long sA, long sB, long sC, long sMask)
{
    __shared__ f16 smem[4 * 16384];   // 4-deep ring: per buf A 8192 + B 8192 f16

    int bx, by, bz;
    if constexpr (GDEC == 0) {
        bx = blockIdx.x; by = blockIdx.y; bz = blockIdx.z;
    } else {
        int l = blockIdx.x;
        bz = l & 7; bx = (l >> 3) & ((1 << LGX) - 1); by = l >> (3 + LGX);
    }
    const f16* Ab = A + (long)bz * sA;
    const f16* Bb = B + (long)bz * sB;
    const int bm0 = by * 256;
    const int bn0 = bx * 256;

    const int tid  = threadIdx.x;
    const int lane = tid & 63;
    const int wid  = tid >> 6;
    const int wm   = (wid >> 2) * 128;   // 2 wave-rows x 128
    const int wn   = (wid & 3)  * 64;    // 4 wave-cols x 64
    const int lr   = lane & 15;
    const int quad = lane >> 4;
    const int kb   = (quad ^ ((lr >> 1) & 3)) << 3;  // swizzled k-block read offset

    const int offA = (wm + lr) * 32 + kb;   // + rg*512
    const int offB = (wn + lr) * 32 + kb;   // + cg*512

    // Staging source pointers: slot n = sweep*512 + tid; r = n>>2, c = n&3;
    // slot holds global k-block c ^ ((r>>1)&3). Sweep 1 = rows +128, same swizzle.
    const int r0 = tid >> 2, c0 = tid & 3;
    const int sw = (c0 ^ ((r0 >> 1) & 3)) << 3;
    const f16* gAs = Ab + (long)(bm0 + r0) * K + sw;
    const f16* gBs = Bb + (long)(bn0 + r0) * K + sw;
    const long sweep = (long)128 * K;

    f16* ldsAw = smem + wid * 512;           // + buf*16384, sweep1 at +4096
    f16* ldsBw = smem + 8192 + wid * 512;

    f32x4 acc[8][4] = {};
    f32x4 rs[8] = {};          // EPI==2: rowsum accumulators (ones-MFMA)
    f16x8 bones;
#pragma unroll
    for (int j = 0; j < 8; ++j) bones[j] = (f16)1.0f;

    const int nt = K >> 5;     // K-tiles of 32; nt >= 4 for all our shapes

    // Prologue: stage tiles 0,1,2 (12 gl_lds); vmcnt(8) -> tile 0 landed.
#pragma unroll
    for (int tt = 0; tt < 3; ++tt) {
        const f16* gA = gAs + (long)tt * 32;
        const f16* gB = gBs + (long)tt * 32;
        f16* dA = ldsAw + tt * 16384;
        f16* dB = ldsBw + tt * 16384;
        gl_lds16(gA, dA);
        gl_lds16(gA + sweep, dA + 4096);
        gl_lds16(gB, dB);
        gl_lds16(gB + sweep, dB + 4096);
    }
    asm volatile("s_waitcnt vmcnt(8)" ::: "memory");
    BAR();

    // Main loop: vmcnt(4) at end of tile t leaves only t+3's loads in flight
    // -> t+2 resident one full tile before its reads.
#pragma unroll 1
    for (int t = 0; t < nt - 3; ++t) {
        TILE_BODY(t, 1, "s_waitcnt vmcnt(4)");
    }
    TILE_BODY(nt - 3, 0, "s_waitcnt vmcnt(4)");
    TILE_BODY(nt - 2, 0, "s_waitcnt vmcnt(0)");
    TILE_BODY(nt - 1, 0, "");

    // Epilogue. C/D layout: col = lane&15, row = quad*4 + reg.
    if constexpr (EPI == 0) {
        f16* C = (f16*)Cv + (long)bz * sC;
#pragma unroll
        for (int rg = 0; rg < 8; ++rg)
#pragma unroll
            for (int cg = 0; cg < 4; ++cg)
#pragma unroll
                for (int r = 0; r < 4; ++r) {
                    long idx = (long)(bm0 + wm + rg * 16 + quad * 4 + r) * N
                             + (bn0 + wn + cg * 16 + lr);
                    C[idx] = (f16)acc[rg][cg][r];
                }
    } else if constexpr (EPI == 1) {
        f16* C = (f16*)Cv + (long)bz * sC;
        const int* Mk = Mask + (long)bz * sMask;
#pragma unroll
        for (int rg = 0; rg < 8; ++rg)
#pragma unroll
            for (int cg = 0; cg < 4; ++cg)
#pragma unroll
                for (int r = 0; r < 4; ++r) {
                    long idx = (long)(bm0 + wm + rg * 16 + quad * 4 + r) * N
                             + (bn0 + wn + cg * 16 + lr);
                    float v = (Mk[idx] == 0) ? -1e10f : acc[rg][cg][r];
                    C[idx] = (f16)__expf(v * 0.03125f);
                }
    } else {
        float* C = (float*)Cv + (long)bz * sC;
#pragma unroll
        for (int rg = 0; rg < 8; ++rg) {
            float inv[4];
#pragma unroll
            for (int r = 0; r < 4; ++r) {
                float s = rs[rg][r];                 // rowsum of row quad*4+r —
                inv[r] = (s > 0.f) ? 1.0f / s : 0.f; // same C/D slot
            }
#pragma unroll
            for (int cg = 0; cg < 4; ++cg)
#pragma unroll
                for (int r = 0; r < 4; ++r) {
                    long idx = (long)(bm0 + wm + rg * 16 + quad * 4 + r) * N
                             + (bn0 + wn + cg * 16 + lr);
                    C[idx] = acc[rg][cg][r] * inv[r];
                }
        }
    }
}

// fp32 -> f16, 4 elem/thread.
__global__ __launch_bounds__(256)
void cvt_f32_f16(const float* __restrict__ src, f16* __restrict__ dst)
{
    long i = ((long)blockIdx.x * 256 + threadIdx.x) * 4;
    float4 v = *(const float4*)(src + i);
    f16x4 o;
    o[0] = (f16)v.x; o[1] = (f16)v.y; o[2] = (f16)v.z; o[3] = (f16)v.w;
    *(f16x4*)(dst + i) = o;
}

// 3 weight matrices (1024x1024 each) in one dispatch: grid 3072.
__global__ __launch_bounds__(256)
void cvt_w3(const float* __restrict__ a, const float* __restrict__ b,
            const float* __restrict__ c,
            f16* __restrict__ oa, f16* __restrict__ ob, f16* __restrict__ oc)
{
    int bid = blockIdx.x;
    const float* s; f16* d;
    if (bid < 1024)      { s = a; d = oa; }
    else if (bid < 2048) { s = b; d = ob; bid -= 1024; }
    else                 { s = c; d = oc; bid -= 2048; }
    long i = ((long)bid * 256 + threadIdx.x) * 4;
    float4 v = *(const float4*)(s + i);
    f16x4 o;
    o[0] = (f16)v.x; o[1] = (f16)v.y; o[2] = (f16)v.z; o[3] = (f16)v.w;
    *(f16x4*)(d + i) = o;
}

extern "C" void kernel_launch(void* const* d_in, const int* in_sizes, int n_in,
                              void* d_out, int out_size, void* d_ws, size_t ws_size,
                              hipStream_t stream)
{
    const float* h1   = (const float*)d_in[0];
    const float* h2   = (const float*)d_in[1];
    const int*   mask = (const int*)d_in[2];
    const float* Wq   = (const float*)d_in[3];
    const float* Wk   = (const float*)d_in[4];
    const float* Wv   = (const float*)d_in[5];
    float* out = (float*)d_out;

    char* ws = (char*)d_ws;
    f16* h1f = (f16*)(ws);
    f16* h2f = (f16*)(ws + 33554432);
    f16* Wqf = (f16*)(ws + 67108864);
    f16* Wkf = (f16*)(ws + 69206016);
    f16* Wvf = (f16*)(ws + 71303168);
    f16* SP  = (f16*)(ws + 33554432);           // over dead h2f+Wf
    f16* Vt  = (f16*)(ws);                      // over dead h1f
    f16* Qf  = (f16*)d_out;
    f16* Kp  = (f16*)((char*)d_out + 33554432);

    dim3 blk(256);
    dim3 blk5(512);

    cvt_f32_f16<<<dim3(16384), blk, 0, stream>>>(h1, h1f);
    cvt_f32_f16<<<dim3(16384), blk, 0, stream>>>(h2, h2f);
    cvt_w3<<<dim3(3072), blk, 0, stream>>>(Wq, Wk, Wv, Wqf, Wkf, Wvf);

    // Q = h1 @ Wq^T  (16384x1024, K=1024) -> d_out lo
    gemm256_nt_f16<0, 0, 0><<<dim3(4, 64, 1), blk5, 0, stream>>>(h1f, Wqf, Qf,
        nullptr, 1024, 1024, 0, 0, 0, 0);
    // K = h2 @ Wk^T  -> d_out hi
    gemm256_nt_f16<0, 0, 0><<<dim3(4, 64, 1), blk5, 0, stream>>>(h2f, Wkf, Kp,
        nullptr, 1024, 1024, 0, 0, 0, 0);
    // Vt[b] = Wv @ h2[b]^T  (1024x2048, K=1024) -> over dead h1f
    gemm256_nt_f16<0, 0, 0><<<dim3(8, 4, 8), blk5, 0, stream>>>(Wvf, h2f, Vt,
        nullptr, 2048, 1024, 0, (long)2048 * 1024, (long)1024 * 2048, 0);
    // P' = exp(mask_scale(Q @ K^T))  (2048x2048, K=1024), 1D xcd grid (LGX=3)
    gemm256_nt_f16<1, 1, 3><<<dim3(512), blk5, 0, stream>>>(Qf, Kp, SP,
        mask, 2048, 1024, (long)2048 * 1024, (long)2048 * 1024,
        (long)2048 * 2048, (long)2048 * 2048);
    // out[b] = (P'[b] @ Vt[b]^T) / rowsum  (2048x1024, K=2048), 1D xcd (LGX=2)
    gemm256_nt_f16<2, 1, 2><<<dim3(256), blk5, 0, stream>>>(SP, Vt, out,
        nullptr, 1024, 2048, (long)2048 * 2048, (long)1024 * 2048,
        (long)2048 * 1024, 0);
}

// Round 3
// 550.004 us; speedup vs baseline: 1.0184x; 1.0184x over previous
//
#include <hip/hip_runtime.h>

// CrossAttention B=8, N=M=2048, D=HID=OUT=1024. fp32 in / fp32 out, int32 mask.
//
// Round-8: round-7 confirmed the K-loop runs at ~800 TF (m248-level for
// 256^2/K=1024 counted-vmcnt). Remaining S-GEMM cost is the SERIALIZED mask
// read in the epilogue (~21 us: 1 block/CU, nothing overlaps it).
// This round:
//   (a) S GEMM (EPI=1): mask bit-prefetch. During the last 16 K-tiles each
//       wave loads its 128 mask dwords (8/tile, issued BEFORE that tile's
//       staging gl_lds so the end-of-tile vmcnt(4) invariant is unchanged:
//       newest-4 outstanding = staging of t+3), packs mask!=0 into 4 VGPRs
//       (128 bits) one tile after issue. Epilogue does no global reads:
//       C = bit ? exp(acc/32) : 0   (bit-identical: expf(-1e10/32)==0.0f).
//   (b) merged the 3 cvt dispatches into one (grid 35840).
// Everything else identical to round-7 (ring-4 counted-vmcnt, 1 barrier/tile,
// XOR swizzle with 0 measured bank conflicts, fused rowsum out-GEMM).
//
// Buffers (peak ws = 100,663,296 B):
//   h1f ws@0           33.5 MB (dead after Q)    -> Vt reuses
//   h2f ws@33,554,432  33.5 MB (dead after Vt)
//   Wf  ws@67,108,864   6.3 MB (dead after Vt)
//   SP  ws@33,554,432  67.1 MB (over dead h2f+Wf)
//   Qf  d_out lo half, Kp d_out hi half (dead before final fp32 write)

using f16   = _Float16;
using f16x4 = __attribute__((ext_vector_type(4))) _Float16;
using f16x8 = __attribute__((ext_vector_type(8))) _Float16;
using f32x4 = __attribute__((ext_vector_type(4))) float;

typedef unsigned int u32_g __attribute__((address_space(1)));
typedef unsigned int u32_l __attribute__((address_space(3)));

__device__ __forceinline__ void gl_lds16(const f16* g, f16* l) {
    __builtin_amdgcn_global_load_lds((const u32_g*)g, (u32_l*)l, 16, 0, 0);
}

#define FENCE() asm volatile("" ::: "memory")
#define BAR()   do { FENCE(); __builtin_amdgcn_s_barrier(); FENCE(); } while (0)

// Mask prefetch helpers (EPI==1 only). linear = rg*16+cg*4+r, idx = u*8+j.
#define MASK_ISSUE(U_)                                                   \
  { int idx0_ = (U_) * 8;                                                \
    _Pragma("unroll")                                                    \
    for (int j_ = 0; j_ < 8; ++j_) {                                     \
      int idx_ = idx0_ + j_;                                             \
      long off_ = (long)(((idx_ >> 4) * 16) + (idx_ & 3)) * N            \
                + (((idx_ >> 2) & 3) * 16);                              \
      mv[j_] = Mrow[off_];                                               \
    } }

#define MASK_PACK(U_)                                                    \
  { unsigned b_ = 0;                                                     \
    _Pragma("unroll")                                                    \
    for (int j_ = 0; j_ < 8; ++j_) b_ |= (mv[j_] != 0 ? 1u : 0u) << j_;  \
    unsigned sh_ = (unsigned)(((U_) & 3) * 8);                           \
    int w_ = (U_) >> 2;                                                  \
    mw[0] |= (w_ == 0) ? (b_ << sh_) : 0u;                               \
    mw[1] |= (w_ == 1) ? (b_ << sh_) : 0u;                               \
    mw[2] |= (w_ == 2) ? (b_ << sh_) : 0u;                               \
    mw[3] |= (w_ == 3) ? (b_ << sh_) : 0u;                               \
  }

// 16 MFMA: rows RG_..RG_+3 x all 4 col-groups (+4 rowsum MFMA for EPI 2).
#define MFMA_HALF(A0_, A1_, A2_, A3_, RG_)                                               \
  do {                                                                                   \
    if constexpr (EPI == 2) {                                                            \
      rs[RG_+0] = __builtin_amdgcn_mfma_f32_16x16x32_f16(A0_, bones, rs[RG_+0], 0,0,0);  \
      rs[RG_+1] = __builtin_amdgcn_mfma_f32_16x16x32_f16(A1_, bones, rs[RG_+1], 0,0,0);  \
      rs[RG_+2] = __builtin_amdgcn_mfma_f32_16x16x32_f16(A2_, bones, rs[RG_+2], 0,0,0);  \
      rs[RG_+3] = __builtin_amdgcn_mfma_f32_16x16x32_f16(A3_, bones, rs[RG_+3], 0,0,0);  \
    }                                                                                    \
    acc[RG_+0][0] = __builtin_amdgcn_mfma_f32_16x16x32_f16(A0_, b0, acc[RG_+0][0],0,0,0);\
    acc[RG_+0][1] = __builtin_amdgcn_mfma_f32_16x16x32_f16(A0_, b1, acc[RG_+0][1],0,0,0);\
    acc[RG_+0][2] = __builtin_amdgcn_mfma_f32_16x16x32_f16(A0_, b2, acc[RG_+0][2],0,0,0);\
    acc[RG_+0][3] = __builtin_amdgcn_mfma_f32_16x16x32_f16(A0_, b3, acc[RG_+0][3],0,0,0);\
    acc[RG_+1][0] = __builtin_amdgcn_mfma_f32_16x16x32_f16(A1_, b0, acc[RG_+1][0],0,0,0);\
    acc[RG_+1][1] = __builtin_amdgcn_mfma_f32_16x16x32_f16(A1_, b1, acc[RG_+1][1],0,0,0);\
    acc[RG_+1][2] = __builtin_amdgcn_mfma_f32_16x16x32_f16(A1_, b2, acc[RG_+1][2],0,0,0);\
    acc[RG_+1][3] = __builtin_amdgcn_mfma_f32_16x16x32_f16(A1_, b3, acc[RG_+1][3],0,0,0);\
    acc[RG_+2][0] = __builtin_amdgcn_mfma_f32_16x16x32_f16(A2_, b0, acc[RG_+2][0],0,0,0);\
    acc[RG_+2][1] = __builtin_amdgcn_mfma_f32_16x16x32_f16(A2_, b1, acc[RG_+2][1],0,0,0);\
    acc[RG_+2][2] = __builtin_amdgcn_mfma_f32_16x16x32_f16(A2_, b2, acc[RG_+2][2],0,0,0);\
    acc[RG_+2][3] = __builtin_amdgcn_mfma_f32_16x16x32_f16(A2_, b3, acc[RG_+2][3],0,0,0);\
    acc[RG_+3][0] = __builtin_amdgcn_mfma_f32_16x16x32_f16(A3_, b0, acc[RG_+3][0],0,0,0);\
    acc[RG_+3][1] = __builtin_amdgcn_mfma_f32_16x16x32_f16(A3_, b1, acc[RG_+3][1],0,0,0);\
    acc[RG_+3][2] = __builtin_amdgcn_mfma_f32_16x16x32_f16(A3_, b2, acc[RG_+3][2],0,0,0);\
    acc[RG_+3][3] = __builtin_amdgcn_mfma_f32_16x16x32_f16(A3_, b3, acc[RG_+3][3],0,0,0);\
  } while (0)

// One K-tile, single region + single barrier. Order matters:
//   [pack prev mask] [issue mask u] [staging gl_lds t+3] [ds_reads] [MFMA]
//   [vmcnt(4)] [barrier]
// Mask loads issue BEFORE staging so the newest-4 outstanding VMEM at the
// vmcnt are exactly t+3's staging loads (ring invariant unchanged); mask
// loads are forced complete by end of their issue tile (~1 tile budget).
#define TILE_BODY(T_, STG_, VM_)                                                         \
  {                                                                                      \
    const f16* bufA_ = smem + ((T_) & 3) * 16384;                                        \
    const f16* bufB_ = bufA_ + 8192;                                                     \
    if constexpr (EPI == 1) {                                                            \
      int u_ = (T_) - WIN0;                                                              \
      if (u_ >= 1) MASK_PACK(u_ - 1);                                                    \
      if (u_ >= 0 && u_ < 16) MASK_ISSUE(u_);                                            \
    }                                                                                    \
    if (STG_) {                                                                          \
      f16* dA_ = ldsAw + ((T_ + 3) & 3) * 16384;                                         \
      f16* dB_ = ldsBw + ((T_ + 3) & 3) * 16384;                                         \
      const f16* gA_ = gAs + (long)(T_ + 3) * 32;                                        \
      const f16* gB_ = gBs + (long)(T_ + 3) * 32;                                        \
      gl_lds16(gA_, dA_);                                                                \
      gl_lds16(gA_ + sweep, dA_ + 4096);                                                 \
      gl_lds16(gB_, dB_);                                                                \
      gl_lds16(gB_ + sweep, dB_ + 4096);                                                 \
    }                                                                                    \
    f16x8 a0_, a1_, a2_, a3_, a4_, a5_, a6_, a7_, b0, b1, b2, b3;                        \
    a0_ = *(const f16x8*)(bufA_ + offA);                                                 \
    a1_ = *(const f16x8*)(bufA_ + offA + 512);                                           \
    a2_ = *(const f16x8*)(bufA_ + offA + 1024);                                          \
    a3_ = *(const f16x8*)(bufA_ + offA + 1536);                                          \
    b0  = *(const f16x8*)(bufB_ + offB);                                                 \
    b1  = *(const f16x8*)(bufB_ + offB + 512);                                           \
    b2  = *(const f16x8*)(bufB_ + offB + 1024);                                          \
    b3  = *(const f16x8*)(bufB_ + offB + 1536);                                          \
    a4_ = *(const f16x8*)(bufA_ + offA + 2048);                                          \
    a5_ = *(const f16x8*)(bufA_ + offA + 2560);                                          \
    a6_ = *(const f16x8*)(bufA_ + offA + 3072);                                          \
    a7_ = *(const f16x8*)(bufA_ + offA + 3584);                                          \
    __builtin_amdgcn_s_setprio(1);                                                       \
    MFMA_HALF(a0_, a1_, a2_, a3_, 0);                                                    \
    MFMA_HALF(a4_, a5_, a6_, a7_, 4);                                                    \
    __builtin_amdgcn_s_setprio(0);                                                       \
    asm volatile(VM_ ::: "memory");                                                      \
    BAR();                                                                               \
  }

// NT GEMM: C = A * B^T. A:(MxK) f16, B:(NxK) f16, row-major. 256x256 tile.
// EPI 0: f16 C.
// EPI 1: f16 C = bit ? exp(acc/32) : 0          [S GEMM, mask bit-prefetch]
// EPI 2: fp32 C = acc / rowsum(A)               [out GEMM, ones-MFMA sums]
// GDEC 0: 3D grid. GDEC 1: 1D grid, z=l&7, x=(l>>3)&(2^LGX-1), y=l>>(3+LGX).
template <int EPI, int GDEC, int LGX>
__global__ __launch_bounds__(512, 2)
void gemm256_nt_f16(const f16* __restrict__ A, const f16* __restrict__ B,
                    void* __restrict__ Cv, const int* __restrict__ Mask,
                    int N, int K, long sA, long sB, long sC, long sMask)
{
    __shared__ f16 smem[4 * 16384];   // 4-deep ring: per buf A 8192 + B 8192 f16

    int bx, by, bz;
    if constexpr (GDEC == 0) {
        bx = blockIdx.x; by = blockIdx.y; bz = blockIdx.z;
    } else {
        int l = blockIdx.x;
        bz = l & 7; bx = (l >> 3) & ((1 << LGX) - 1); by = l >> (3 + LGX);
    }
    const f16* Ab = A + (long)bz * sA;
    const f16* Bb = B + (long)bz * sB;
    const int bm0 = by * 256;
    const int bn0 = bx * 256;

    const int tid  = threadIdx.x;
    const int lane = tid & 63;
    const int wid  = tid >> 6;
    const int wm   = (wid >> 2) * 128;   // 2 wave-rows x 128
    const int wn   = (wid & 3)  * 64;    // 4 wave-cols x 64
    const int lr   = lane & 15;
    const int quad = lane >> 4;
    const int kb   = (quad ^ ((lr >> 1) & 3)) << 3;  // swizzled k-block read offset

    const int offA = (wm + lr) * 32 + kb;   // + rg*512
    const int offB = (wn + lr) * 32 + kb;   // + cg*512

    // Staging source pointers: slot n = sweep*512 + tid; r = n>>2, c = n&3;
    // slot holds global k-block c ^ ((r>>1)&3). Sweep 1 = rows +128, same swizzle.
    const int r0 = tid >> 2, c0 = tid & 3;
    const int sw = (c0 ^ ((r0 >> 1) & 3)) << 3;
    const f16* gAs = Ab + (long)(bm0 + r0) * K + sw;
    const f16* gBs = Bb + (long)(bn0 + r0) * K + sw;
    const long sweep = (long)128 * K;

    f16* ldsAw = smem + wid * 512;           // + buf*16384, sweep1 at +4096
    f16* ldsBw = smem + 8192 + wid * 512;

    f32x4 acc[8][4] = {};
    f32x4 rs[8] = {};          // EPI==2: rowsum accumulators (ones-MFMA)
    f16x8 bones;
#pragma unroll
    for (int j = 0; j < 8; ++j) bones[j] = (f16)1.0f;

    const int nt = K >> 5;     // K-tiles of 32; EPI==1 requires nt >= 19
    const int WIN0 = nt - 16;  // mask prefetch window start (EPI==1)

    // Mask prefetch state (EPI==1 only; dead-code-eliminated otherwise).
    int mv[8];
    unsigned mw[4] = {0u, 0u, 0u, 0u};
    const int* Mrow = Mask + (long)bz * sMask
                    + (long)(bm0 + wm + quad * 4) * N + (bn0 + wn + lr);

    // Prologue: stage tiles 0,1,2 (12 gl_lds); vmcnt(8) -> tile 0 landed.
#pragma unroll
    for (int tt = 0; tt < 3; ++tt) {
        const f16* gA = gAs + (long)tt * 32;
        const f16* gB = gBs + (long)tt * 32;
        f16* dA = ldsAw + tt * 16384;
        f16* dB = ldsBw + tt * 16384;
        gl_lds16(gA, dA);
        gl_lds16(gA + sweep, dA + 4096);
        gl_lds16(gB, dB);
        gl_lds16(gB + sweep, dB + 4096);
    }
    asm volatile("s_waitcnt vmcnt(8)" ::: "memory");
    BAR();

    // Main loop: vmcnt(4) at end of tile t leaves only t+3's staging loads in
    // flight -> t+2 resident one full tile before its reads.
#pragma unroll 1
    for (int t = 0; t < nt - 3; ++t) {
        TILE_BODY(t, 1, "s_waitcnt vmcnt(4)");
    }
    TILE_BODY(nt - 3, 0, "s_waitcnt vmcnt(4)");
    TILE_BODY(nt - 2, 0, "s_waitcnt vmcnt(0)");
    TILE_BODY(nt - 1, 0, "");

    if constexpr (EPI == 1) MASK_PACK(15);   // pack loads issued at tile nt-1

    // Epilogue. C/D layout: col = lane&15, row = quad*4 + reg.
    if constexpr (EPI == 0) {
        f16* C = (f16*)Cv + (long)bz * sC;
#pragma unroll
        for (int rg = 0; rg < 8; ++rg)
#pragma unroll
            for (int cg = 0; cg < 4; ++cg)
#pragma unroll
                for (int r = 0; r < 4; ++r) {
                    long idx = (long)(bm0 + wm + rg * 16 + quad * 4 + r) * N
                             + (bn0 + wn + cg * 16 + lr);
                    C[idx] = (f16)acc[rg][cg][r];
                }
    } else if constexpr (EPI == 1) {
        f16* C = (f16*)Cv + (long)bz * sC;
#pragma unroll
        for (int rg = 0; rg < 8; ++rg)
#pragma unroll
            for (int cg = 0; cg < 4; ++cg)
#pragma unroll
                for (int r = 0; r < 4; ++r) {
                    const int linear = rg * 16 + cg * 4 + r;
                    bool keep = (mw[linear >> 5] >> (linear & 31)) & 1u;
                    long idx = (long)(bm0 + wm + rg * 16 + quad * 4 + r) * N
                             + (bn0 + wn + cg * 16 + lr);
                    float e = __expf(acc[rg][cg][r] * 0.03125f);
                    C[idx] = keep ? (f16)e : (f16)0.0f;  // == exp(-1e10/32)
                }
    } else {
        float* C = (float*)Cv + (long)bz * sC;
#pragma unroll
        for (int rg = 0; rg < 8; ++rg) {
            float inv[4];
#pragma unroll
            for (int r = 0; r < 4; ++r) {
                float s = rs[rg][r];                 // rowsum of row quad*4+r —
                inv[r] = (s > 0.f) ? 1.0f / s : 0.f; // same C/D slot
            }
#pragma unroll
            for (int cg = 0; cg < 4; ++cg)
#pragma unroll
                for (int r = 0; r < 4; ++r) {
                    long idx = (long)(bm0 + wm + rg * 16 + quad * 4 + r) * N
                             + (bn0 + wn + cg * 16 + lr);
                    C[idx] = acc[rg][cg][r] * inv[r];
                }
        }
    }
}

// fp32 -> f16 for all five inputs in ONE dispatch. Grid 35840 blocks:
//   [0,16384) h1, [16384,32768) h2, then 1024 each for Wq, Wk, Wv.
__global__ __launch_bounds__(256)
void cvt_all(const float* __restrict__ h1, const float* __restrict__ h2,
             const float* __restrict__ wq, const float* __restrict__ wk,
             const float* __restrict__ wv,
             f16* __restrict__ oh1, f16* __restrict__ oh2,
             f16* __restrict__ owq, f16* __restrict__ owk,
             f16* __restrict__ owv)
{
    int bid = blockIdx.x;
    const float* s; f16* d;
    if (bid < 16384)      { s = h1; d = oh1; }
    else if (bid < 32768) { s = h2; d = oh2; bid -= 16384; }
    else if (bid < 33792) { s = wq; d = owq; bid -= 32768; }
    else if (bid < 34816) { s = wk; d = owk; bid -= 33792; }
    else                  { s = wv; d = owv; bid -= 34816; }
    long i = ((long)bid * 256 + threadIdx.x) * 4;
    float4 v = *(const float4*)(s + i);
    f16x4 o;
    o[0] = (f16)v.x; o[1] = (f16)v.y; o[2] = (f16)v.z; o[3] = (f16)v.w;
    *(f16x4*)(d + i) = o;
}

extern "C" void kernel_launch(void* const* d_in, const int* in_sizes, int n_in,
                              void* d_out, int out_size, void* d_ws, size_t ws_size,
                              hipStream_t stream)
{
    const float* h1   = (const float*)d_in[0];
    const float* h2   = (const float*)d_in[1];
    const int*   mask = (const int*)d_in[2];
    const float* Wq   = (const float*)d_in[3];
    const float* Wk   = (const float*)d_in[4];
    const float* Wv   = (const float*)d_in[5];
    float* out = (float*)d_out;

    char* ws = (char*)d_ws;
    f16* h1f = (f16*)(ws);
    f16* h2f = (f16*)(ws + 33554432);
    f16* Wqf = (f16*)(ws + 67108864);
    f16* Wkf = (f16*)(ws + 69206016);
    f16* Wvf = (f16*)(ws + 71303168);
    f16* SP  = (f16*)(ws + 33554432);           // over dead h2f+Wf
    f16* Vt  = (f16*)(ws);                      // over dead h1f
    f16* Qf  = (f16*)d_out;
    f16* Kp  = (f16*)((char*)d_out + 33554432);

    dim3 blk(256);
    dim3 blk5(512);

    cvt_all<<<dim3(35840), blk, 0, stream>>>(h1, h2, Wq, Wk, Wv,
                                             h1f, h2f, Wqf, Wkf, Wvf);

    // Q = h1 @ Wq^T  (16384x1024, K=1024) -> d_out lo
    gemm256_nt_f16<0, 0, 0><<<dim3(4, 64, 1), blk5, 0, stream>>>(h1f, Wqf, Qf,
        nullptr, 1024, 1024, 0, 0, 0, 0);
    // K = h2 @ Wk^T  -> d_out hi
    gemm256_nt_f16<0, 0, 0><<<dim3(4, 64, 1), blk5, 0, stream>>>(h2f, Wkf, Kp,
        nullptr, 1024, 1024, 0, 0, 0, 0);
    // Vt[b] = Wv @ h2[b]^T  (1024x2048, K=1024) -> over dead h1f
    gemm256_nt_f16<0, 0, 0><<<dim3(8, 4, 8), blk5, 0, stream>>>(Wvf, h2f, Vt,
        nullptr, 2048, 1024, 0, (long)2048 * 1024, (long)1024 * 2048, 0);
    // P' = exp(mask_scale(Q @ K^T))  (2048x2048, K=1024), 1D xcd grid (LGX=3)
    gemm256_nt_f16<1, 1, 3><<<dim3(512), blk5, 0, stream>>>(Qf, Kp, SP,
        mask, 2048, 1024, (long)2048 * 1024, (long)2048 * 1024,
        (long)2048 * 2048, (long)2048 * 2048);
    // out[b] = (P'[b] @ Vt[b]^T) / rowsum  (2048x1024, K=2048), 1D xcd (LGX=2)
    gemm256_nt_f16<2, 1, 2><<<dim3(256), blk5, 0, stream>>>(SP, Vt, out,
        nullptr, 1024, 2048, (long)2048 * 2048, (long)1024 * 2048,
        (long)2048 * 1024, 0);
}